// Round 8
// baseline (327.388 us; speedup 1.0000x reference)
//
#include <hip/hip_runtime.h>

typedef unsigned short u16;
typedef unsigned int u32;
typedef float f32x4 __attribute__((ext_vector_type(4)));
typedef float f32x16 __attribute__((ext_vector_type(16)));
typedef __bf16 bf16x8 __attribute__((ext_vector_type(8)));
typedef u32 u32x4 __attribute__((ext_vector_type(4)));

__device__ __forceinline__ u16 f2bf(float f) {
  u32 u = __builtin_bit_cast(u32, f);
  u32 r = (u + 0x7fffu + ((u >> 16) & 1u)) >> 16;
  return (u16)r;
}

__device__ __forceinline__ u32 pk2bf(float lo, float hi_) {
  u32 r;
  asm("v_cvt_pk_bf16_f32 %0, %1, %2" : "=v"(r) : "v"(lo), "v"(hi_));
  return r;
}

__device__ __forceinline__ void plswap(u32 &a, u32 &b) {
#if __has_builtin(__builtin_amdgcn_permlane32_swap)
  auto r = __builtin_amdgcn_permlane32_swap(a, b, false, false);
  a = r[0]; b = r[1];
#else
  asm volatile("v_permlane32_swap_b32 %0, %1" : "+v"(a), "+v"(b));
#endif
}

__device__ __forceinline__ float xhalf_max(float x) {
  u32 a = __builtin_bit_cast(u32, x), b = a;
  plswap(a, b);
  return fmaxf(__builtin_bit_cast(float, a), __builtin_bit_cast(float, b));
}
__device__ __forceinline__ float xhalf_sum(float x) {
  u32 a = __builtin_bit_cast(u32, x), b = a;
  plswap(a, b);
  return __builtin_bit_cast(float, a) + __builtin_bit_cast(float, b);
}

// async global->LDS, 16B per lane (dest = uniform base + lane*16)
__device__ __forceinline__ void gll16(const u16* g, u16* l) {
  __builtin_amdgcn_global_load_lds(
      (const __attribute__((address_space(1))) void*)g,
      (__attribute__((address_space(3))) void*)l, 16, 0, 0);
}

// ---------------- fp32 -> bf16 conversion (x, Wq|Wkv concat, Wo) ----------------
__global__ __launch_bounds__(256) void cvt_kernel(
    const float4* __restrict__ x, const float4* __restrict__ wq,
    const float4* __restrict__ wkv, const float4* __restrict__ wo,
    uint2* __restrict__ xb, uint2* __restrict__ wqkvb, uint2* __restrict__ wob) {
  long i = (long)blockIdx.x * 256 + threadIdx.x;
  const float4* src; uint2* dst; long off;
  if (i < 1048576)      { src = x;   dst = xb;             off = i; }
  else if (i < 1310720) { src = wq;  dst = wqkvb;          off = i - 1048576; }
  else if (i < 1441792) { src = wkv; dst = wqkvb + 262144; off = i - 1310720; }
  else                  { src = wo;  dst = wob;            off = i - 1441792; }
  float4 v = src[off];
  uint2 o;
  o.x = ((u32)f2bf(v.y) << 16) | (u32)f2bf(v.x);
  o.y = ((u32)f2bf(v.w) << 16) | (u32)f2bf(v.z);
  dst[off] = o;
}

// ---------------- 2-phase double-buffered 128x128 bf16 GEMM core ----------------
__device__ __forceinline__ void gemm_core(
    const u16* __restrict__ A, const u16* __restrict__ W, const int K,
    f32x4 acc[4][4], u16* As, u16* Ws) {
  const int t = threadIdx.x, lane = t & 63, w = t >> 6;
  const int wm = (w >> 1) * 64, wn = (w & 1) * 64;
  const long bm = (long)blockIdx.x * 128, bn = (long)blockIdx.y * 128;
  const int cc = lane & 15, kg8 = (lane >> 4) * 8;

  const int srow = w * 32 + (lane >> 2);
  const int scol = (lane & 3) * 8;
  const u16* Ag0 = &A[(bm + srow) * (long)K + scol];
  const u16* Ag1 = Ag0 + 16 * (long)K;
  const u16* Wg0 = &W[(bn + srow) * (long)K + scol];
  const u16* Wg1 = Wg0 + 16 * (long)K;
  const int lbase = w * 32 * 32;

#pragma unroll
  for (int i = 0; i < 4; i++)
#pragma unroll
    for (int j = 0; j < 4; j++) acc[i][j] = f32x4{0.f, 0.f, 0.f, 0.f};

  // prologue: stage tile 0 into buffer 0
  gll16(Ag0, As + lbase);
  gll16(Ag1, As + lbase + 512);
  gll16(Wg0, Ws + lbase);
  gll16(Wg1, Ws + lbase + 512);
  __syncthreads();

  const int nt = K / 32;
  for (int ti = 0; ti < nt; ti++) {
    const int cur = (ti & 1) * 4096;
    const int nxt = cur ^ 4096;
    if (ti + 1 < nt) {
      const int k0 = (ti + 1) * 32;
      gll16(Ag0 + k0, As + nxt + lbase);
      gll16(Ag1 + k0, As + nxt + lbase + 512);
      gll16(Wg0 + k0, Ws + nxt + lbase);
      gll16(Wg1 + k0, Ws + nxt + lbase + 512);
    }
    bf16x8 af[4], wf[4];
#pragma unroll
    for (int i = 0; i < 4; i++) af[i] = *(const bf16x8*)&As[cur + (wm + i * 16 + cc) * 32 + kg8];
#pragma unroll
    for (int j = 0; j < 4; j++) wf[j] = *(const bf16x8*)&Ws[cur + (wn + j * 16 + cc) * 32 + kg8];
#pragma unroll
    for (int i = 0; i < 4; i++)
#pragma unroll
      for (int j = 0; j < 4; j++)
        acc[i][j] = __builtin_amdgcn_mfma_f32_16x16x32_bf16(af[i], wf[j], acc[i][j], 0, 0, 0);
    __syncthreads();   // drains next-tile loads + all waves done reading cur
  }
}

// ---------------- GEMM1: qkv projection + routing epilogue ----------------
__global__ __launch_bounds__(256) void gemm_qkv_kernel(
    const u16* __restrict__ A, const u16* __restrict__ W,
    u16* __restrict__ Qb, u16* __restrict__ Kb, u16* __restrict__ VTb) {
  __shared__ __align__(16) u16 As[8192];
  __shared__ __align__(16) u16 Ws[8192];
  f32x4 acc[4][4];
  gemm_core(A, W, 1024, acc, As, Ws);
  const int t = threadIdx.x, lane = t & 63, w = t >> 6;
  const int wm = (w >> 1) * 64, wn = (w & 1) * 64;
  const int bm = blockIdx.x * 128, bn = blockIdx.y * 128;
  const int rr = (lane >> 4) * 4, cc = lane & 15;
#pragma unroll
  for (int i = 0; i < 4; i++)
#pragma unroll
    for (int jf = 0; jf < 4; jf++)
#pragma unroll
      for (int j = 0; j < 4; j++) {
        int m = bm + wm + i * 16 + rr + j;
        int n = bn + wn + jf * 16 + cc;
        float v = acc[i][jf][j];
        if (n < 1024) {
          Qb[(long)m * 1024 + n] = f2bf(v * 0.18033688011112043f);  // 0.125*log2(e)
        } else {
          int c = n - 1024, g = c >> 7, rm = c & 127;
          int b = m >> 11, pos = m & 2047;
          long base = (long)(b * 4 + g);
          if (rm < 64) Kb[(base * 2048 + pos) * 64 + rm] = f2bf(v);
          else         VTb[(base * 64 + (rm - 64)) * 2048 + pos] = f2bf(v);
        }
      }
}

// ---------------- GEMM2: output projection, fp32 out ----------------
__global__ __launch_bounds__(256) void gemm_out_kernel(
    const u16* __restrict__ A, const u16* __restrict__ W, float* __restrict__ out) {
  __shared__ __align__(16) u16 As[8192];
  __shared__ __align__(16) u16 Ws[8192];
  f32x4 acc[4][4];
  gemm_core(A, W, 1024, acc, As, Ws);
  const int t = threadIdx.x, lane = t & 63, w = t >> 6;
  const int wm = (w >> 1) * 64, wn = (w & 1) * 64;
  const int bm = blockIdx.x * 128, bn = blockIdx.y * 128;
  const int rr = (lane >> 4) * 4, cc = lane & 15;
#pragma unroll
  for (int i = 0; i < 4; i++)
#pragma unroll
    for (int jf = 0; jf < 4; jf++)
#pragma unroll
      for (int j = 0; j < 4; j++) {
        int m = bm + wm + i * 16 + rr + j;
        int n = bn + wn + jf * 16 + cc;
        out[(long)m * 1024 + n] = acc[i][jf][j];
      }
}

// ---------------- flash attention (causal + ALiBi, GQA) ----------------
// Swapped-operand 32x32x16, in-register softmax, branch-free hot loop.
// amdgpu_waves_per_eu(4,4): pins the allocator target at 4 waves/EU (128
// VGPR budget). Without the max bound, hipcc's occupancy heuristic targets
// 64 VGPR (8 waves/EU) and SPILLS the early-V/K live state to scratch:
// R7 measured 400MB of scratch traffic, attn 206us vs R5's 112us.
__global__ __launch_bounds__(256) __attribute__((amdgpu_waves_per_eu(4, 4)))
void attn_kernel(
    const u16* __restrict__ Q, const u16* __restrict__ Kb,
    const u16* __restrict__ VTb, u16* __restrict__ AT) {
  __shared__ __align__(16) float Ol[4][32][36];
  __shared__ float ml[4][2][32];

  const int t = threadIdx.x, lane = t & 63, w = t >> 6;
  const int qt = 63 - (int)blockIdx.x;   // LPT: longest blocks first
  const int h = blockIdx.y, b = blockIdx.z;
  const int g = h >> 2;
  const int lam = lane & 31, hi = lane >> 5;
  const int qrow0 = qt * 32;
  const int kblocks = (qrow0 + 95) >> 6;
  const int jb_max = kblocks - 1;

  const u16* Qrow = Q + ((long)(b * 2048 + qrow0 + lam)) * 1024 + h * 64 + hi * 8;
  bf16x8 qf0 = *(const bf16x8*)(Qrow);
  bf16x8 qf1 = *(const bf16x8*)(Qrow + 16);
  bf16x8 qf2 = *(const bf16x8*)(Qrow + 32);
  bf16x8 qf3 = *(const bf16x8*)(Qrow + 48);

  const u16* Kg = Kb  + ((long)(b * 4 + g)) * 2048 * 64;
  const u16* Vg = VTb + ((long)(b * 4 + g)) * 64 * 2048;

  f32x16 zv;
#pragma unroll
  for (int i = 0; i < 16; i++) zv[i] = 0.f;
  f32x16 acc0 = zv, acc1 = zv;

  const float slope2 = exp2f(-0.5f * (float)(h + 1)) * 1.44269504f;
  float m = slope2 * (float)(qrow0 + lam);   // shift value at the diagonal
  float lsum = 0.f;

  auto tile = [&](int kbase, bool masked) {
    // ---- QK^T (swapped): S^T[key][qrow] ----
    const u16* Ka = Kg + (long)(kbase + lam) * 64 + hi * 8;
    bf16x8 k0 = *(const bf16x8*)(Ka);
    bf16x8 k1 = *(const bf16x8*)(Ka + 16);
    bf16x8 k2 = *(const bf16x8*)(Ka + 32);
    bf16x8 k3 = *(const bf16x8*)(Ka + 48);
    f32x16 s0 = zv;
    s0 = __builtin_amdgcn_mfma_f32_32x32x16_bf16(k0, qf0, s0, 0, 0, 0);
    s0 = __builtin_amdgcn_mfma_f32_32x32x16_bf16(k1, qf1, s0, 0, 0, 0);
    s0 = __builtin_amdgcn_mfma_f32_32x32x16_bf16(k2, qf2, s0, 0, 0, 0);
    s0 = __builtin_amdgcn_mfma_f32_32x32x16_bf16(k3, qf3, s0, 0, 0, 0);
    const bool t1v = !masked || (kbase + 32 <= qrow0 + 31);
    f32x16 s1;
    if (t1v) {
      const u16* Kc = Ka + 32 * 64;
      bf16x8 c0 = *(const bf16x8*)(Kc);
      bf16x8 c1 = *(const bf16x8*)(Kc + 16);
      bf16x8 c2 = *(const bf16x8*)(Kc + 32);
      bf16x8 c3 = *(const bf16x8*)(Kc + 48);
      s1 = zv;
      s1 = __builtin_amdgcn_mfma_f32_32x32x16_bf16(c0, qf0, s1, 0, 0, 0);
      s1 = __builtin_amdgcn_mfma_f32_32x32x16_bf16(c1, qf1, s1, 0, 0, 0);
      s1 = __builtin_amdgcn_mfma_f32_32x32x16_bf16(c2, qf2, s1, 0, 0, 0);
      s1 = __builtin_amdgcn_mfma_f32_32x32x16_bf16(c3, qf3, s1, 0, 0, 0);
    } else {
#pragma unroll
      for (int r = 0; r < 16; r++) s1[r] = -1e30f;
    }

    // ---- V loads issued NOW; consumed after softmax (latency hidden) ----
    const u16* Va = Vg + (long)lam * 2048 + kbase + hi * 8;
    bf16x8 vA0 = *(const bf16x8*)(Va);
    bf16x8 vA1 = *(const bf16x8*)(Va + 16);
    bf16x8 vA2 = *(const bf16x8*)(Va + 32);
    bf16x8 vA3 = *(const bf16x8*)(Va + 48);
    bf16x8 vB0 = *(const bf16x8*)(Va + 65536);
    bf16x8 vB1 = *(const bf16x8*)(Va + 65536 + 16);
    bf16x8 vB2 = *(const bf16x8*)(Va + 65536 + 32);
    bf16x8 vB3 = *(const bf16x8*)(Va + 65536 + 48);

    // ---- ALiBi (+ causal mask only on the boundary tile) ----
    const float ks0 = slope2 * (float)(kbase + 4 * hi);
    const float ks1 = ks0 + slope2 * 32.f;
    if (masked) {
      const float db0 = (float)(kbase + 4 * hi - qrow0 - lam);
#pragma unroll
      for (int r = 0; r < 16; r++) {
        const float rbf = (float)((r & 3) + 8 * (r >> 2));
        const float d0 = db0 + rbf;
        s0[r] = (d0 > 0.f) ? -1e30f : s0[r] + (ks0 + slope2 * rbf);
        s1[r] = (d0 + 32.f > 0.f) ? -1e30f : s1[r] + (ks1 + slope2 * rbf);
      }
    } else {
#pragma unroll
      for (int r = 0; r < 16; r++) {
        const float rbf = (float)((r & 3) + 8 * (r >> 2));
        s0[r] += ks0 + slope2 * rbf;
        s1[r] += ks1 + slope2 * rbf;
      }
    }

    // ---- online softmax ----
    float red[8];
#pragma unroll
    for (int i = 0; i < 8; i++)
      red[i] = fmaxf(fmaxf(s0[i], s0[i + 8]), fmaxf(s1[i], s1[i + 8]));
#pragma unroll
    for (int i = 0; i < 4; i++) red[i] = fmaxf(red[i], red[i + 4]);
    float pm = fmaxf(fmaxf(red[0], red[1]), fmaxf(red[2], red[3]));
    pm = xhalf_max(pm);
    if (!__all(pm <= m + 8.f)) {       // T13 defer-max: P bounded by 2^8
      const float mnew = fmaxf(m, pm);
      const float al = exp2f(m - mnew);
      m = mnew;
      lsum *= al;
      acc0 *= al;
      acc1 *= al;
    }
#pragma unroll
    for (int r = 0; r < 16; r++) s0[r] = exp2f(s0[r] - m);
#pragma unroll
    for (int r = 0; r < 16; r++) s1[r] = exp2f(s1[r] - m);
    {
      float sr[8];
#pragma unroll
      for (int i = 0; i < 8; i++) sr[i] = (s0[i] + s0[i + 8]) + (s1[i] + s1[i + 8]);
#pragma unroll
      for (int i = 0; i < 4; i++) sr[i] += sr[i + 4];
      lsum += xhalf_sum((sr[0] + sr[1]) + (sr[2] + sr[3]));
    }

    // ---- P -> B-frags -> O^T += V^T * P ----
    {
      u32 wd[8];
#pragma unroll
      for (int i = 0; i < 8; i++) wd[i] = pk2bf(s0[2 * i], s0[2 * i + 1]);
      plswap(wd[0], wd[2]); plswap(wd[1], wd[3]);
      plswap(wd[4], wd[6]); plswap(wd[5], wd[7]);
      bf16x8 pf0 = __builtin_bit_cast(bf16x8, u32x4{wd[0], wd[1], wd[2], wd[3]});
      bf16x8 pf1 = __builtin_bit_cast(bf16x8, u32x4{wd[4], wd[5], wd[6], wd[7]});
      acc0 = __builtin_amdgcn_mfma_f32_32x32x16_bf16(vA0, pf0, acc0, 0, 0, 0);
      acc0 = __builtin_amdgcn_mfma_f32_32x32x16_bf16(vA1, pf1, acc0, 0, 0, 0);
      acc1 = __builtin_amdgcn_mfma_f32_32x32x16_bf16(vB0, pf0, acc1, 0, 0, 0);
      acc1 = __builtin_amdgcn_mfma_f32_32x32x16_bf16(vB1, pf1, acc1, 0, 0, 0);
    }
    if (t1v) {
      u32 wd[8];
#pragma unroll
      for (int i = 0; i < 8; i++) wd[i] = pk2bf(s1[2 * i], s1[2 * i + 1]);
      plswap(wd[0], wd[2]); plswap(wd[1], wd[3]);
      plswap(wd[4], wd[6]); plswap(wd[5], wd[7]);
      bf16x8 pf0 = __builtin_bit_cast(bf16x8, u32x4{wd[0], wd[1], wd[2], wd[3]});
      bf16x8 pf1 = __builtin_bit_cast(bf16x8, u32x4{wd[4], wd[5], wd[6], wd[7]});
      acc0 = __builtin_amdgcn_mfma_f32_32x32x16_bf16(vA2, pf0, acc0, 0, 0, 0);
      acc0 = __builtin_amdgcn_mfma_f32_32x32x16_bf16(vA3, pf1, acc0, 0, 0, 0);
      acc1 = __builtin_amdgcn_mfma_f32_32x32x16_bf16(vB2, pf0, acc1, 0, 0, 0);
      acc1 = __builtin_amdgcn_mfma_f32_32x32x16_bf16(vB3, pf1, acc1, 0, 0, 0);
    }
  };

  // descending keys; wave with jb0 == jb_max owns the (single) boundary tile
  int jb = (kblocks > w) ? (w + (((kblocks - 1 - w) >> 2) << 2)) : -1;
  if (jb == jb_max && jb >= 0) { tile(jb * 64, true); jb -= 4; }
  for (; jb >= 0; jb -= 4) tile(jb * 64, false);

  // ---- two-phase cross-wave combine ----
#pragma unroll
  for (int rq = 0; rq < 4; rq++)
    *(f32x4*)&Ol[w][lam][8 * rq + 4 * hi] =
        f32x4{acc0[4 * rq], acc0[4 * rq + 1], acc0[4 * rq + 2], acc0[4 * rq + 3]};
  if (hi == 0) { ml[w][0][lam] = m; ml[w][1][lam] = lsum; }
  __syncthreads();

  const int r = t >> 3, c0 = (t & 7) * 4;
  float M = fmaxf(fmaxf(ml[0][0][r], ml[1][0][r]), fmaxf(ml[2][0][r], ml[3][0][r]));
  float sc[4];
  float L = 0.f;
#pragma unroll
  for (int ww = 0; ww < 4; ww++) {
    sc[ww] = exp2f(ml[ww][0][r] - M);
    L += sc[ww] * ml[ww][1][r];
  }
  const float inv = 1.f / L;
  {
    float o[4] = {0.f, 0.f, 0.f, 0.f};
#pragma unroll
    for (int ww = 0; ww < 4; ww++)
#pragma unroll
      for (int i = 0; i < 4; i++) o[i] += sc[ww] * Ol[ww][r][c0 + i];
    uint2 ov;
    ov.x = ((u32)f2bf(o[1] * inv) << 16) | f2bf(o[0] * inv);
    ov.y = ((u32)f2bf(o[3] * inv) << 16) | f2bf(o[2] * inv);
    *(uint2*)&AT[((long)(b * 2048 + qrow0 + r)) * 1024 + h * 64 + c0] = ov;
  }
  __syncthreads();   // Ol reads done; safe to overwrite with acc1
#pragma unroll
  for (int rq = 0; rq < 4; rq++)
    *(f32x4*)&Ol[w][lam][8 * rq + 4 * hi] =
        f32x4{acc1[4 * rq], acc1[4 * rq + 1], acc1[4 * rq + 2], acc1[4 * rq + 3]};
  __syncthreads();
  {
    float o[4] = {0.f, 0.f, 0.f, 0.f};
#pragma unroll
    for (int ww = 0; ww < 4; ww++)
#pragma unroll
      for (int i = 0; i < 4; i++) o[i] += sc[ww] * Ol[ww][r][c0 + i];
    uint2 ov;
    ov.x = ((u32)f2bf(o[1] * inv) << 16) | f2bf(o[0] * inv);
    ov.y = ((u32)f2bf(o[3] * inv) << 16) | f2bf(o[2] * inv);
    *(uint2*)&AT[((long)(b * 2048 + qrow0 + r)) * 1024 + h * 64 + 32 + c0] = ov;
  }
}

// ---------------- launcher ----------------
extern "C" void kernel_launch(void* const* d_in, const int* in_sizes, int n_in,
                              void* d_out, int out_size, void* d_ws, size_t ws_size,
                              hipStream_t stream) {
  const float* x   = (const float*)d_in[0];
  const float* Wq  = (const float*)d_in[1];
  const float* Wkv = (const float*)d_in[2];
  const float* Wo  = (const float*)d_in[3];
  float* out = (float*)d_out;
  char* ws = (char*)d_ws;

  u16* xb    = (u16*)(ws);
  u16* wqkvb = (u16*)(ws + 8388608);
  u16* wob   = (u16*)(ws + 11534336);
  u16* Qb    = (u16*)(ws + 13631488);
  u16* Kb    = (u16*)(ws + 22020096);
  u16* VTb   = (u16*)(ws + 24117248);
  u16* AT    = (u16*)(ws + 26214400);

  cvt_kernel<<<6656, 256, 0, stream>>>(
      (const float4*)x, (const float4*)Wq, (const float4*)Wkv, (const float4*)Wo,
      (uint2*)xb, (uint2*)wqkvb, (uint2*)wob);

  gemm_qkv_kernel<<<dim3(32, 12), 256, 0, stream>>>(xb, wqkvb, Qb, Kb, VTb);

  attn_kernel<<<dim3(64, 16, 2), 256, 0, stream>>>(Qb, Kb, VTb, AT);

  gemm_out_kernel<<<dim3(32, 8), 256, 0, stream>>>(AT, wob, out);
}

// Round 10
// 224.969 us; speedup vs baseline: 1.4553x; 1.4553x over previous
//
#include <hip/hip_runtime.h>

typedef unsigned short u16;
typedef unsigned int u32;
typedef float f32x4 __attribute__((ext_vector_type(4)));
typedef float f32x16 __attribute__((ext_vector_type(16)));
typedef __bf16 bf16x8 __attribute__((ext_vector_type(8)));
typedef u32 u32x4 __attribute__((ext_vector_type(4)));

__device__ __forceinline__ u16 f2bf(float f) {
  u32 u = __builtin_bit_cast(u32, f);
  u32 r = (u + 0x7fffu + ((u >> 16) & 1u)) >> 16;
  return (u16)r;
}

__device__ __forceinline__ u32 pk2bf(float lo, float hi_) {
  u32 r;
  asm("v_cvt_pk_bf16_f32 %0, %1, %2" : "=v"(r) : "v"(lo), "v"(hi_));
  return r;
}

__device__ __forceinline__ void plswap(u32 &a, u32 &b) {
#if __has_builtin(__builtin_amdgcn_permlane32_swap)
  auto r = __builtin_amdgcn_permlane32_swap(a, b, false, false);
  a = r[0]; b = r[1];
#else
  asm volatile("v_permlane32_swap_b32 %0, %1" : "+v"(a), "+v"(b));
#endif
}

__device__ __forceinline__ float xhalf_max(float x) {
  u32 a = __builtin_bit_cast(u32, x), b = a;
  plswap(a, b);
  return fmaxf(__builtin_bit_cast(float, a), __builtin_bit_cast(float, b));
}
__device__ __forceinline__ float xhalf_sum(float x) {
  u32 a = __builtin_bit_cast(u32, x), b = a;
  plswap(a, b);
  return __builtin_bit_cast(float, a) + __builtin_bit_cast(float, b);
}

// async global->LDS, 16B per lane (dest = uniform base + lane*16)
__device__ __forceinline__ void gll16(const u16* g, u16* l) {
  __builtin_amdgcn_global_load_lds(
      (const __attribute__((address_space(1))) void*)g,
      (__attribute__((address_space(3))) void*)l, 16, 0, 0);
}

// ---------------- fp32 -> bf16 conversion (x, Wq|Wkv concat, Wo) ----------------
__global__ __launch_bounds__(256) void cvt_kernel(
    const float4* __restrict__ x, const float4* __restrict__ wq,
    const float4* __restrict__ wkv, const float4* __restrict__ wo,
    uint2* __restrict__ xb, uint2* __restrict__ wqkvb, uint2* __restrict__ wob) {
  long i = (long)blockIdx.x * 256 + threadIdx.x;
  const float4* src; uint2* dst; long off;
  if (i < 1048576)      { src = x;   dst = xb;             off = i; }
  else if (i < 1310720) { src = wq;  dst = wqkvb;          off = i - 1048576; }
  else if (i < 1441792) { src = wkv; dst = wqkvb + 262144; off = i - 1310720; }
  else                  { src = wo;  dst = wob;            off = i - 1441792; }
  float4 v = src[off];
  uint2 o;
  o.x = ((u32)f2bf(v.y) << 16) | (u32)f2bf(v.x);
  o.y = ((u32)f2bf(v.w) << 16) | (u32)f2bf(v.z);
  dst[off] = o;
}

// ---------------- 64x128 double-buffered bf16 GEMM core (C = A * W^T) ----------------
// Smaller M-tile -> 2-3x more blocks -> cross-block TLP hides the per-barrier
// vmcnt drain (R5-R8 GEMM2 had exactly 1 block/CU: zero overlap, fully exposed
// latency). Per wave: 32x64 output = 2x4 frags; 3 gll16 + 6 ds_read_b128 +
// 8 MFMA per K-step. LDS: A 2x4KB + W 2x8KB = 24KB.
__device__ __forceinline__ void gemm_core(
    const u16* __restrict__ A, const u16* __restrict__ W, const int K,
    f32x4 acc[2][4], u16* As, u16* Ws) {
  const int t = threadIdx.x, lane = t & 63, w = t >> 6;
  const int wm = (w >> 1) * 32, wn = (w & 1) * 64;
  const long bm = (long)blockIdx.x * 64, bn = (long)blockIdx.y * 128;
  const int cc = lane & 15, kg8 = (lane >> 4) * 8;

  const int scol = (lane & 3) * 8;
  const u16* Ag  = &A[(bm + w * 16 + (lane >> 2)) * (long)K + scol];
  const u16* Wg0 = &W[(bn + w * 32 + (lane >> 2)) * (long)K + scol];
  const u16* Wg1 = Wg0 + 16 * (long)K;

#pragma unroll
  for (int i = 0; i < 2; i++)
#pragma unroll
    for (int j = 0; j < 4; j++) acc[i][j] = f32x4{0.f, 0.f, 0.f, 0.f};

  // prologue: stage tile 0 into buffer 0
  gll16(Ag, As + w * 512);
  gll16(Wg0, Ws + w * 1024);
  gll16(Wg1, Ws + w * 1024 + 512);
  __syncthreads();

  const int nt = K / 32;
  for (int ti = 0; ti < nt; ti++) {
    const int curA = (ti & 1) * 2048;
    const int curW = (ti & 1) * 4096;
    if (ti + 1 < nt) {
      const int k0 = (ti + 1) * 32;
      gll16(Ag + k0, As + (curA ^ 2048) + w * 512);
      gll16(Wg0 + k0, Ws + (curW ^ 4096) + w * 1024);
      gll16(Wg1 + k0, Ws + (curW ^ 4096) + w * 1024 + 512);
    }
    bf16x8 af[2], wf[4];
#pragma unroll
    for (int i = 0; i < 2; i++) af[i] = *(const bf16x8*)&As[curA + (wm + i * 16 + cc) * 32 + kg8];
#pragma unroll
    for (int j = 0; j < 4; j++) wf[j] = *(const bf16x8*)&Ws[curW + (wn + j * 16 + cc) * 32 + kg8];
#pragma unroll
    for (int i = 0; i < 2; i++)
#pragma unroll
      for (int j = 0; j < 4; j++)
        acc[i][j] = __builtin_amdgcn_mfma_f32_16x16x32_bf16(af[i], wf[j], acc[i][j], 0, 0, 0);
    __syncthreads();   // drains next-tile loads + all waves done reading cur
  }
}

// ---------------- GEMM1: qkv projection + routing epilogue ----------------
__global__ __launch_bounds__(256) void gemm_qkv_kernel(
    const u16* __restrict__ A, const u16* __restrict__ W,
    u16* __restrict__ Qb, u16* __restrict__ Kb, u16* __restrict__ VTb) {
  __shared__ __align__(16) u16 As[4096];
  __shared__ __align__(16) u16 Ws[8192];
  f32x4 acc[2][4];
  gemm_core(A, W, 1024, acc, As, Ws);
  const int t = threadIdx.x, lane = t & 63, w = t >> 6;
  const int wm = (w >> 1) * 32, wn = (w & 1) * 64;
  const int bm = blockIdx.x * 64, bn = blockIdx.y * 128;
  const int rr = (lane >> 4) * 4, cc = lane & 15;
#pragma unroll
  for (int i = 0; i < 2; i++)
#pragma unroll
    for (int jf = 0; jf < 4; jf++)
#pragma unroll
      for (int j = 0; j < 4; j++) {
        int m = bm + wm + i * 16 + rr + j;
        int n = bn + wn + jf * 16 + cc;
        float v = acc[i][jf][j];
        if (n < 1024) {
          Qb[(long)m * 1024 + n] = f2bf(v * 0.18033688011112043f);  // 0.125*log2(e)
        } else {
          int c = n - 1024, g = c >> 7, rm = c & 127;
          int b = m >> 11, pos = m & 2047;
          long base = (long)(b * 4 + g);
          if (rm < 64) Kb[(base * 2048 + pos) * 64 + rm] = f2bf(v);
          else         VTb[(base * 64 + (rm - 64)) * 2048 + pos] = f2bf(v);
        }
      }
}

// ---------------- GEMM2: output projection, fp32 out ----------------
__global__ __launch_bounds__(256) void gemm_out_kernel(
    const u16* __restrict__ A, const u16* __restrict__ W, float* __restrict__ out) {
  __shared__ __align__(16) u16 As[4096];
  __shared__ __align__(16) u16 Ws[8192];
  f32x4 acc[2][4];
  gemm_core(A, W, 1024, acc, As, Ws);
  const int t = threadIdx.x, lane = t & 63, w = t >> 6;
  const int wm = (w >> 1) * 32, wn = (w & 1) * 64;
  const int bm = blockIdx.x * 64, bn = blockIdx.y * 128;
  const int rr = (lane >> 4) * 4, cc = lane & 15;
#pragma unroll
  for (int i = 0; i < 2; i++)
#pragma unroll
    for (int jf = 0; jf < 4; jf++)
#pragma unroll
      for (int j = 0; j < 4; j++) {
        int m = bm + wm + i * 16 + rr + j;
        int n = bn + wn + jf * 16 + cc;
        out[(long)m * 1024 + n] = acc[i][jf][j];
      }
}

// ---------------- flash attention (causal + ALiBi, GQA) ----------------
// Swapped-operand 32x32x16, in-register softmax, peeled boundary tile,
// ALiBi row-shift cancellation. V loads AFTER softmax: gfx950's unified
// VGPR file means 128-total cap at 4 waves/EU; acc(32)+scores(32)+Q(16)
// +K(16) is already ~128 -- hoisting V (+32) spills 400MB to scratch
// (R7/R8 measured). s_setprio(1) around MFMA clusters (T5, indep waves).
__global__ __launch_bounds__(256, 4) void attn_kernel(
    const u16* __restrict__ Q, const u16* __restrict__ Kb,
    const u16* __restrict__ VTb, u16* __restrict__ AT) {
  __shared__ __align__(16) float Ol[4][32][36];
  __shared__ float ml[4][2][32];

  const int t = threadIdx.x, lane = t & 63, w = t >> 6;
  const int qt = 63 - (int)blockIdx.x;   // LPT: longest blocks first
  const int h = blockIdx.y, b = blockIdx.z;
  const int g = h >> 2;
  const int lam = lane & 31, hi = lane >> 5;
  const int qrow0 = qt * 32;
  const int kblocks = (qrow0 + 95) >> 6;
  const int jb_max = kblocks - 1;

  const u16* Qrow = Q + ((long)(b * 2048 + qrow0 + lam)) * 1024 + h * 64 + hi * 8;
  bf16x8 qf0 = *(const bf16x8*)(Qrow);
  bf16x8 qf1 = *(const bf16x8*)(Qrow + 16);
  bf16x8 qf2 = *(const bf16x8*)(Qrow + 32);
  bf16x8 qf3 = *(const bf16x8*)(Qrow + 48);

  const u16* Kg = Kb  + ((long)(b * 4 + g)) * 2048 * 64;
  const u16* Vg = VTb + ((long)(b * 4 + g)) * 64 * 2048;

  f32x16 zv;
#pragma unroll
  for (int i = 0; i < 16; i++) zv[i] = 0.f;
  f32x16 acc0 = zv, acc1 = zv;

  const float slope2 = exp2f(-0.5f * (float)(h + 1)) * 1.44269504f;
  float m = slope2 * (float)(qrow0 + lam);   // shift value at the diagonal
  float lsum = 0.f;

  auto tile = [&](int kbase, bool masked) {
    // ---- QK^T (swapped): S^T[key][qrow] ----
    const u16* Ka = Kg + (long)(kbase + lam) * 64 + hi * 8;
    bf16x8 k0 = *(const bf16x8*)(Ka);
    bf16x8 k1 = *(const bf16x8*)(Ka + 16);
    bf16x8 k2 = *(const bf16x8*)(Ka + 32);
    bf16x8 k3 = *(const bf16x8*)(Ka + 48);
    f32x16 s0 = zv;
    __builtin_amdgcn_s_setprio(1);
    s0 = __builtin_amdgcn_mfma_f32_32x32x16_bf16(k0, qf0, s0, 0, 0, 0);
    s0 = __builtin_amdgcn_mfma_f32_32x32x16_bf16(k1, qf1, s0, 0, 0, 0);
    s0 = __builtin_amdgcn_mfma_f32_32x32x16_bf16(k2, qf2, s0, 0, 0, 0);
    s0 = __builtin_amdgcn_mfma_f32_32x32x16_bf16(k3, qf3, s0, 0, 0, 0);
    __builtin_amdgcn_s_setprio(0);
    const bool t1v = !masked || (kbase + 32 <= qrow0 + 31);
    f32x16 s1;
    if (t1v) {
      const u16* Kc = Ka + 32 * 64;
      bf16x8 c0 = *(const bf16x8*)(Kc);
      bf16x8 c1 = *(const bf16x8*)(Kc + 16);
      bf16x8 c2 = *(const bf16x8*)(Kc + 32);
      bf16x8 c3 = *(const bf16x8*)(Kc + 48);
      s1 = zv;
      __builtin_amdgcn_s_setprio(1);
      s1 = __builtin_amdgcn_mfma_f32_32x32x16_bf16(c0, qf0, s1, 0, 0, 0);
      s1 = __builtin_amdgcn_mfma_f32_32x32x16_bf16(c1, qf1, s1, 0, 0, 0);
      s1 = __builtin_amdgcn_mfma_f32_32x32x16_bf16(c2, qf2, s1, 0, 0, 0);
      s1 = __builtin_amdgcn_mfma_f32_32x32x16_bf16(c3, qf3, s1, 0, 0, 0);
      __builtin_amdgcn_s_setprio(0);
    } else {
#pragma unroll
      for (int r = 0; r < 16; r++) s1[r] = -1e30f;
    }

    // ---- ALiBi (+ causal mask only on the boundary tile) ----
    const float ks0 = slope2 * (float)(kbase + 4 * hi);
    const float ks1 = ks0 + slope2 * 32.f;
    if (masked) {
      const float db0 = (float)(kbase + 4 * hi - qrow0 - lam);
#pragma unroll
      for (int r = 0; r < 16; r++) {
        const float rbf = (float)((r & 3) + 8 * (r >> 2));
        const float d0 = db0 + rbf;
        s0[r] = (d0 > 0.f) ? -1e30f : s0[r] + (ks0 + slope2 * rbf);
        s1[r] = (d0 + 32.f > 0.f) ? -1e30f : s1[r] + (ks1 + slope2 * rbf);
      }
    } else {
#pragma unroll
      for (int r = 0; r < 16; r++) {
        const float rbf = (float)((r & 3) + 8 * (r >> 2));
        s0[r] += ks0 + slope2 * rbf;
        s1[r] += ks1 + slope2 * rbf;
      }
    }

    // ---- online softmax ----
    float red[8];
#pragma unroll
    for (int i = 0; i < 8; i++)
      red[i] = fmaxf(fmaxf(s0[i], s0[i + 8]), fmaxf(s1[i], s1[i + 8]));
#pragma unroll
    for (int i = 0; i < 4; i++) red[i] = fmaxf(red[i], red[i + 4]);
    float pm = fmaxf(fmaxf(red[0], red[1]), fmaxf(red[2], red[3]));
    pm = xhalf_max(pm);
    if (!__all(pm <= m + 8.f)) {       // T13 defer-max: P bounded by 2^8
      const float mnew = fmaxf(m, pm);
      const float al = exp2f(m - mnew);
      m = mnew;
      lsum *= al;
      acc0 *= al;
      acc1 *= al;
    }
#pragma unroll
    for (int r = 0; r < 16; r++) s0[r] = exp2f(s0[r] - m);
#pragma unroll
    for (int r = 0; r < 16; r++) s1[r] = exp2f(s1[r] - m);
    {
      float sr[8];
#pragma unroll
      for (int i = 0; i < 8; i++) sr[i] = (s0[i] + s0[i + 8]) + (s1[i] + s1[i + 8]);
#pragma unroll
      for (int i = 0; i < 4; i++) sr[i] += sr[i + 4];
      lsum += xhalf_sum((sr[0] + sr[1]) + (sr[2] + sr[3]));
    }

    // ---- P -> B-frags; V loaded here (post-softmax: fits 128-reg cap) ----
    const u16* Va = Vg + (long)lam * 2048 + kbase + hi * 8;
    {
      u32 wd[8];
#pragma unroll
      for (int i = 0; i < 8; i++) wd[i] = pk2bf(s0[2 * i], s0[2 * i + 1]);
      plswap(wd[0], wd[2]); plswap(wd[1], wd[3]);
      plswap(wd[4], wd[6]); plswap(wd[5], wd[7]);
      bf16x8 pf0 = __builtin_bit_cast(bf16x8, u32x4{wd[0], wd[1], wd[2], wd[3]});
      bf16x8 pf1 = __builtin_bit_cast(bf16x8, u32x4{wd[4], wd[5], wd[6], wd[7]});
      bf16x8 v00 = *(const bf16x8*)(Va);
      bf16x8 v01 = *(const bf16x8*)(Va + 16);
      bf16x8 v10 = *(const bf16x8*)(Va + 65536);
      bf16x8 v11 = *(const bf16x8*)(Va + 65536 + 16);
      __builtin_amdgcn_s_setprio(1);
      acc0 = __builtin_amdgcn_mfma_f32_32x32x16_bf16(v00, pf0, acc0, 0, 0, 0);
      acc0 = __builtin_amdgcn_mfma_f32_32x32x16_bf16(v01, pf1, acc0, 0, 0, 0);
      acc1 = __builtin_amdgcn_mfma_f32_32x32x16_bf16(v10, pf0, acc1, 0, 0, 0);
      acc1 = __builtin_amdgcn_mfma_f32_32x32x16_bf16(v11, pf1, acc1, 0, 0, 0);
      __builtin_amdgcn_s_setprio(0);
    }
    if (t1v) {
      u32 wd[8];
#pragma unroll
      for (int i = 0; i < 8; i++) wd[i] = pk2bf(s1[2 * i], s1[2 * i + 1]);
      plswap(wd[0], wd[2]); plswap(wd[1], wd[3]);
      plswap(wd[4], wd[6]); plswap(wd[5], wd[7]);
      bf16x8 pf0 = __builtin_bit_cast(bf16x8, u32x4{wd[0], wd[1], wd[2], wd[3]});
      bf16x8 pf1 = __builtin_bit_cast(bf16x8, u32x4{wd[4], wd[5], wd[6], wd[7]});
      bf16x8 v02 = *(const bf16x8*)(Va + 32);
      bf16x8 v03 = *(const bf16x8*)(Va + 48);
      bf16x8 v12 = *(const bf16x8*)(Va + 65536 + 32);
      bf16x8 v13 = *(const bf16x8*)(Va + 65536 + 48);
      __builtin_amdgcn_s_setprio(1);
      acc0 = __builtin_amdgcn_mfma_f32_32x32x16_bf16(v02, pf0, acc0, 0, 0, 0);
      acc0 = __builtin_amdgcn_mfma_f32_32x32x16_bf16(v03, pf1, acc0, 0, 0, 0);
      acc1 = __builtin_amdgcn_mfma_f32_32x32x16_bf16(v12, pf0, acc1, 0, 0, 0);
      acc1 = __builtin_amdgcn_mfma_f32_32x32x16_bf16(v13, pf1, acc1, 0, 0, 0);
      __builtin_amdgcn_s_setprio(0);
    }
  };

  // descending keys; wave with jb0 == jb_max owns the (single) boundary tile
  int jb = (kblocks > w) ? (w + (((kblocks - 1 - w) >> 2) << 2)) : -1;
  if (jb == jb_max && jb >= 0) { tile(jb * 64, true); jb -= 4; }
  for (; jb >= 0; jb -= 4) tile(jb * 64, false);

  // ---- two-phase cross-wave combine ----
#pragma unroll
  for (int rq = 0; rq < 4; rq++)
    *(f32x4*)&Ol[w][lam][8 * rq + 4 * hi] =
        f32x4{acc0[4 * rq], acc0[4 * rq + 1], acc0[4 * rq + 2], acc0[4 * rq + 3]};
  if (hi == 0) { ml[w][0][lam] = m; ml[w][1][lam] = lsum; }
  __syncthreads();

  const int r = t >> 3, c0 = (t & 7) * 4;
  float M = fmaxf(fmaxf(ml[0][0][r], ml[1][0][r]), fmaxf(ml[2][0][r], ml[3][0][r]));
  float sc[4];
  float L = 0.f;
#pragma unroll
  for (int ww = 0; ww < 4; ww++) {
    sc[ww] = exp2f(ml[ww][0][r] - M);
    L += sc[ww] * ml[ww][1][r];
  }
  const float inv = 1.f / L;
  {
    float o[4] = {0.f, 0.f, 0.f, 0.f};
#pragma unroll
    for (int ww = 0; ww < 4; ww++)
#pragma unroll
      for (int i = 0; i < 4; i++) o[i] += sc[ww] * Ol[ww][r][c0 + i];
    uint2 ov;
    ov.x = ((u32)f2bf(o[1] * inv) << 16) | f2bf(o[0] * inv);
    ov.y = ((u32)f2bf(o[3] * inv) << 16) | f2bf(o[2] * inv);
    *(uint2*)&AT[((long)(b * 2048 + qrow0 + r)) * 1024 + h * 64 + c0] = ov;
  }
  __syncthreads();   // Ol reads done; safe to overwrite with acc1
#pragma unroll
  for (int rq = 0; rq < 4; rq++)
    *(f32x4*)&Ol[w][lam][8 * rq + 4 * hi] =
        f32x4{acc1[4 * rq], acc1[4 * rq + 1], acc1[4 * rq + 2], acc1[4 * rq + 3]};
  __syncthreads();
  {
    float o[4] = {0.f, 0.f, 0.f, 0.f};
#pragma unroll
    for (int ww = 0; ww < 4; ww++)
#pragma unroll
      for (int i = 0; i < 4; i++) o[i] += sc[ww] * Ol[ww][r][c0 + i];
    uint2 ov;
    ov.x = ((u32)f2bf(o[1] * inv) << 16) | f2bf(o[0] * inv);
    ov.y = ((u32)f2bf(o[3] * inv) << 16) | f2bf(o[2] * inv);
    *(uint2*)&AT[((long)(b * 2048 + qrow0 + r)) * 1024 + h * 64 + 32 + c0] = ov;
  }
}

// ---------------- launcher ----------------
extern "C" void kernel_launch(void* const* d_in, const int* in_sizes, int n_in,
                              void* d_out, int out_size, void* d_ws, size_t ws_size,
                              hipStream_t stream) {
  const float* x   = (const float*)d_in[0];
  const float* Wq  = (const float*)d_in[1];
  const float* Wkv = (const float*)d_in[2];
  const float* Wo  = (const float*)d_in[3];
  float* out = (float*)d_out;
  char* ws = (char*)d_ws;

  u16* xb    = (u16*)(ws);
  u16* wqkvb = (u16*)(ws + 8388608);
  u16* wob   = (u16*)(ws + 11534336);
  u16* Qb    = (u16*)(ws + 13631488);
  u16* Kb    = (u16*)(ws + 22020096);
  u16* VTb   = (u16*)(ws + 24117248);
  u16* AT    = (u16*)(ws + 26214400);

  cvt_kernel<<<6656, 256, 0, stream>>>(
      (const float4*)x, (const float4*)Wq, (const float4*)Wkv, (const float4*)Wo,
      (uint2*)xb, (uint2*)wqkvb, (uint2*)wob);

  gemm_qkv_kernel<<<dim3(64, 12), 256, 0, stream>>>(xb, wqkvb, Qb, Kb, VTb);

  attn_kernel<<<dim3(64, 16, 2), 256, 0, stream>>>(Qb, Kb, VTb, AT);

  gemm_out_kernel<<<dim3(64, 8), 256, 0, stream>>>(AT, wob, out);
}